// Round 3
// baseline (15564.940 us; speedup 1.0000x reference)
//
#include <hip/hip_runtime.h>
#include <stdint.h>

#define T_STEPS 512
#define NB 64
#define HID 1024
#define G4 4096
#define NBLK_STEP 64

typedef __attribute__((ext_vector_type(8))) short bf16x8;
typedef __attribute__((ext_vector_type(4))) float f32x4;

__device__ inline unsigned short f2bf(float f) {
  unsigned int u = __float_as_uint(f);
  return (unsigned short)((u + 0x7fffu + ((u >> 16) & 1u)) >> 16);
}
__device__ inline unsigned int pack2bf(float lo, float hi) {
  return (unsigned int)f2bf(lo) | ((unsigned int)f2bf(hi) << 16);
}

// async global->LDS, 16B per lane, wave-uniform LDS base (m97 pattern)
#define GLOAD_LDS16(g, l) \
  __builtin_amdgcn_global_load_lds((const __attribute__((address_space(1))) void*)(g), \
                                   (__attribute__((address_space(3))) void*)(l), 16, 0, 0)

// ---------------- fp32 -> bf16 (W_ih / W_hh) ----------------
__global__ __launch_bounds__(256) void cvt_bf16_kernel(const float4* __restrict__ src,
                                                       ushort4* __restrict__ dst) {
  int i = blockIdx.x * 256 + threadIdx.x;
  float4 v = src[i];
  ushort4 r;
  r.x = f2bf(v.x); r.y = f2bf(v.y); r.z = f2bf(v.z); r.w = f2bf(v.w);
  dst[i] = r;
}

// ---------------- fp32 -> bf16 chunk of x, rows remapped to b*TC+dt ----------------
__global__ __launch_bounds__(256) void cvt_x_chunk(const float* __restrict__ x,
                                                   unsigned short* __restrict__ xbf,
                                                   int t0, int tclog2) {
  int i = blockIdx.x * 256 + threadIdx.x;   // one per 8 elems
  int e8 = i * 8;
  int row = e8 >> 10;                        // b*TC + dt
  int col = e8 & 1023;
  int b = row >> tclog2;
  int dt = row & ((1 << tclog2) - 1);
  const float* src = x + ((size_t)(b * T_STEPS + t0 + dt) << 10) + col;
  float4 v0 = *(const float4*)src;
  float4 v1 = *(const float4*)(src + 4);
  uint4 p;
  p.x = pack2bf(v0.x, v0.y); p.y = pack2bf(v0.z, v0.w);
  p.z = pack2bf(v1.x, v1.y); p.w = pack2bf(v1.z, v1.w);
  *(uint4*)(xbf + e8) = p;
}

// ---------------- zero-init c-state, h double buffer, barrier ----------------
__global__ __launch_bounds__(256) void init_state_kernel(float* __restrict__ c_state,
                                                         unsigned short* __restrict__ h_buf,
                                                         unsigned int* __restrict__ bar) {
  int i = blockIdx.x * 256 + threadIdx.x;   // 131072 threads
  if (i < NB * HID) c_state[i] = 0.0f;
  h_buf[i] = 0;                              // both h buffers
  if (i < 32) bar[i] = 0;
}

// ---------------- phase 1: chunk GEMM, m97-style async staging ----------------
// A = xbf [NB*TC][1024] bf16, B = W_ih bf16 [4096][1024]; C = fp32 [NB*TC][4096]+bias.
// 128x128 tile, BK=32, 4 waves 2x2, LDS unpadded [row][32] (required by global_load_lds).
__global__ __launch_bounds__(256, 2) void gemm_xproj_chunk(
    const unsigned short* __restrict__ xbf,
    const unsigned short* __restrict__ Wih,
    const float* __restrict__ b_ih,
    const float* __restrict__ b_hh,
    float* __restrict__ Cc) {
  __shared__ unsigned short As[128 * 32];
  __shared__ unsigned short Bs[128 * 32];
  const int tid = threadIdx.x;
  const int m0 = blockIdx.x * 128;
  const int n0 = blockIdx.y * 128;
  const int wave = tid >> 6, lane = tid & 63;
  const int wm = (wave & 1) * 64, wn = (wave >> 1) * 64;
  const int lq = lane >> 4, lr = lane & 15;
  // staging: one global_load_lds covers 16 rows x 64B; wave w does chunks {2w,2w+1}
  const int c0 = wave * 2;
  const unsigned short* gA = xbf + (size_t)(m0 + c0 * 16 + (lane >> 2)) * 1024 + (lane & 3) * 8;
  const unsigned short* gB = Wih + (size_t)(n0 + c0 * 16 + (lane >> 2)) * 1024 + (lane & 3) * 8;
  unsigned short* lA0 = As + c0 * 512;
  unsigned short* lB0 = Bs + c0 * 512;
  f32x4 acc[4][4] = {};
  for (int kk = 0; kk < 1024; kk += 32) {
    __syncthreads();                 // prev iter's fragment reads complete
    GLOAD_LDS16(gA + kk, lA0);
    GLOAD_LDS16(gA + kk + 16 * 1024, lA0 + 512);
    GLOAD_LDS16(gB + kk, lB0);
    GLOAD_LDS16(gB + kk + 16 * 1024, lB0 + 512);
    __syncthreads();                 // staging visible (vmcnt(0) before barrier)
    bf16x8 af[4], bfr[4];
    #pragma unroll
    for (int i = 0; i < 4; ++i) {
      af[i]  = *(const bf16x8*)(As + (wm + i * 16 + lr) * 32 + lq * 8);
      bfr[i] = *(const bf16x8*)(Bs + (wn + i * 16 + lr) * 32 + lq * 8);
    }
    #pragma unroll
    for (int mt = 0; mt < 4; ++mt)
      #pragma unroll
      for (int nt = 0; nt < 4; ++nt)
        acc[mt][nt] = __builtin_amdgcn_mfma_f32_16x16x32_bf16(af[mt], bfr[nt], acc[mt][nt], 0, 0, 0);
  }
  // epilogue: D[m=(lane>>4)*4+r][n=lane&15]
  #pragma unroll
  for (int nt = 0; nt < 4; ++nt) {
    int col = n0 + wn + nt * 16 + lr;
    float bias = b_ih[col] + b_hh[col];
    #pragma unroll
    for (int mt = 0; mt < 4; ++mt) {
      int rb = m0 + wm + mt * 16 + lq * 4;
      #pragma unroll
      for (int r = 0; r < 4; ++r)
        Cc[(size_t)(rb + r) * G4 + col] = acc[mt][nt][r] + bias;
    }
  }
}

// ---------------- grid barrier (64 co-resident blocks, agent scope) ----------------
__device__ inline void grid_barrier(unsigned int* bar) {
  __syncthreads();                    // all waves' stores drained (vmcnt) before arrival
  if (threadIdx.x == 0) {
    __builtin_amdgcn_fence(__ATOMIC_RELEASE, "agent");
    unsigned int gen = __hip_atomic_load(&bar[1], __ATOMIC_RELAXED, __HIP_MEMORY_SCOPE_AGENT);
    unsigned int old = __hip_atomic_fetch_add(&bar[0], 1u, __ATOMIC_RELAXED, __HIP_MEMORY_SCOPE_AGENT);
    if (old == NBLK_STEP - 1) {
      __hip_atomic_store(&bar[0], 0u, __ATOMIC_RELAXED, __HIP_MEMORY_SCOPE_AGENT);
      __hip_atomic_fetch_add(&bar[1], 1u, __ATOMIC_RELAXED, __HIP_MEMORY_SCOPE_AGENT);
    } else {
      while (__hip_atomic_load(&bar[1], __ATOMIC_RELAXED, __HIP_MEMORY_SCOPE_AGENT) == gen)
        __builtin_amdgcn_s_sleep(1);
    }
    __builtin_amdgcn_fence(__ATOMIC_ACQUIRE, "agent");
  }
  __syncthreads();
}

// ---------------- phase 2: persistent TC-step kernel ----------------
// 64 blocks x 256 thr, 1 block/CU. Block u owns units [16u,16u+16); wave = gate
// (0=f,1=i,2=o,3=g). W_hh frags register-resident for all TC steps; c in registers.
__global__ __launch_bounds__(256, 1) void lstm_steps_kernel(
    const unsigned short* __restrict__ Whh,   // bf16 [4096][1024]
    const float* __restrict__ xc,             // chunk [NB*TC][4096] fp32
    unsigned short* __restrict__ h_buf,       // bf16 double buffer [2][64][1024]
    float* __restrict__ c_state,              // fp32 [64][1024]
    float* __restrict__ out,                  // fp32 [64*512][1024]
    unsigned int* __restrict__ bar,
    int t0, int tclog2) {
  __shared__ float gb[4][NB][16];
  const int tid = threadIdx.x;
  const int u = blockIdx.x;
  const int wave = tid >> 6, lane = tid & 63;
  const int lq = lane >> 4, lr = lane & 15;
  const int rowbase = wave * HID + u * 16;
  const unsigned short* wrow = Whh + (size_t)(rowbase + lr) * HID + lq * 8;
  bf16x8 wf[32];
  #pragma unroll
  for (int kk = 0; kk < 32; ++kk) wf[kk] = *(const bf16x8*)(wrow + kk * 32);
  const int bu = tid >> 4, nn = tid & 15;
  float creg[4];
  #pragma unroll
  for (int j = 0; j < 4; ++j) creg[j] = c_state[(bu + 16 * j) * HID + u * 16 + nn];
  const int TC = 1 << tclog2;
  for (int dt = 0; dt < TC; ++dt) {
    const unsigned short* h_in = h_buf + (size_t)(dt & 1) * (NB * HID);
    unsigned short* h_out      = h_buf + (size_t)((dt + 1) & 1) * (NB * HID);
    // issue xproj loads early so they overlap the MFMA chain
    float xp[4][4];
    #pragma unroll
    for (int mt = 0; mt < 4; ++mt)
      #pragma unroll
      for (int r = 0; r < 4; ++r) {
        int b = mt * 16 + lq * 4 + r;
        xp[mt][r] = xc[(size_t)((b << tclog2) + dt) * G4 + rowbase + lr];
      }
    f32x4 accA[4] = {}, accB[4] = {};
    #pragma unroll
    for (int mt = 0; mt < 4; ++mt) {
      const unsigned short* hp = h_in + (size_t)(mt * 16 + lr) * HID + lq * 8;
      #pragma unroll
      for (int kk = 0; kk < 32; kk += 2) {
        bf16x8 a0 = *(const bf16x8*)(hp + kk * 32);
        bf16x8 a1 = *(const bf16x8*)(hp + kk * 32 + 32);
        accA[mt] = __builtin_amdgcn_mfma_f32_16x16x32_bf16(a0, wf[kk], accA[mt], 0, 0, 0);
        accB[mt] = __builtin_amdgcn_mfma_f32_16x16x32_bf16(a1, wf[kk + 1], accB[mt], 0, 0, 0);
      }
    }
    #pragma unroll
    for (int mt = 0; mt < 4; ++mt) {
      f32x4 a = accA[mt] + accB[mt];
      #pragma unroll
      for (int r = 0; r < 4; ++r) {
        float pre = a[r] + xp[mt][r];
        float v;
        if (wave == 3) v = 2.0f / (1.0f + __expf(-2.0f * pre)) - 1.0f;  // tanh
        else           v = 1.0f / (1.0f + __expf(-pre));                 // sigmoid
        gb[wave][mt * 16 + lq * 4 + r][lr] = v;
      }
    }
    __syncthreads();
    const int t = t0 + dt;
    #pragma unroll
    for (int j = 0; j < 4; ++j) {
      int b = bu + 16 * j;
      float f = gb[0][b][nn], i = gb[1][b][nn], o = gb[2][b][nn], g = gb[3][b][nn];
      float c = f * creg[j] + i * g;
      creg[j] = c;
      float th = 2.0f / (1.0f + __expf(-2.0f * c)) - 1.0f;
      float h = o * th;
      out[((size_t)b * T_STEPS + t) * HID + u * 16 + nn] = h;
      h_out[b * HID + u * 16 + nn] = f2bf(h);
    }
    grid_barrier(bar);   // h_out visible device-wide before next step's reads
  }
  #pragma unroll
  for (int j = 0; j < 4; ++j) c_state[(bu + 16 * j) * HID + u * 16 + nn] = creg[j];
}

extern "C" void kernel_launch(void* const* d_in, const int* in_sizes, int n_in,
                              void* d_out, int out_size, void* d_ws, size_t ws_size,
                              hipStream_t stream) {
  const float* x    = (const float*)d_in[0];
  const float* W_ih = (const float*)d_in[1];
  const float* W_hh = (const float*)d_in[2];
  const float* b_ih = (const float*)d_in[3];
  const float* b_hh = (const float*)d_in[4];
  float* out = (float*)d_out;
  char* ws = (char*)d_ws;

  const size_t wih_bytes = (size_t)G4 * HID * 2;   // 8 MB
  const size_t whh_bytes = (size_t)G4 * HID * 2;   // 8 MB
  const size_t c_bytes   = (size_t)NB * HID * 4;   // 256 KB
  const size_t h_bytes   = (size_t)2 * NB * HID * 2;
  const size_t bar_bytes = 128;
  const size_t fixed = wih_bytes + whh_bytes + c_bytes + h_bytes + bar_bytes;
  // adaptive time-chunk: largest TC in {64..2} that fits ws_size
  int tclog2 = 6;
  while (tclog2 > 1) {
    size_t need = fixed + (((size_t)NB << tclog2) * G4 * 4)       // fp32 chunk
                        + (((size_t)NB << tclog2) * HID * 2);     // bf16 x chunk
    if (need <= ws_size) break;
    --tclog2;
  }
  const int TC = 1 << tclog2;

  size_t off = 0;
  float* chunk = (float*)(ws + off);                  off += ((size_t)NB << tclog2) * G4 * 4;
  unsigned short* xbf = (unsigned short*)(ws + off);  off += ((size_t)NB << tclog2) * HID * 2;
  unsigned short* wihb = (unsigned short*)(ws + off); off += wih_bytes;
  unsigned short* whhb = (unsigned short*)(ws + off); off += whh_bytes;
  float* c_state = (float*)(ws + off);                off += c_bytes;
  unsigned short* h_buf = (unsigned short*)(ws + off); off += h_bytes;
  unsigned int* bar = (unsigned int*)(ws + off);

  init_state_kernel<<<512, 256, 0, stream>>>(c_state, h_buf, bar);
  cvt_bf16_kernel<<<4096, 256, 0, stream>>>((const float4*)W_ih, (ushort4*)wihb);
  cvt_bf16_kernel<<<4096, 256, 0, stream>>>((const float4*)W_hh, (ushort4*)whhb);

  const int n_chunks = T_STEPS >> tclog2;
  for (int c = 0; c < n_chunks; ++c) {
    const int t0 = c << tclog2;
    cvt_x_chunk<<<(NB << tclog2) / 2, 256, 0, stream>>>(x, xbf, t0, tclog2);
    gemm_xproj_chunk<<<dim3((NB << tclog2) / 128, 32), 256, 0, stream>>>(
        xbf, wihb, b_ih, b_hh, chunk);
    lstm_steps_kernel<<<NBLK_STEP, 256, 0, stream>>>(whhb, chunk, h_buf, c_state,
                                                     out, bar, t0, tclog2);
  }
}